// Round 4
// baseline (45.082 us; speedup 1.0000x reference)
//
#include <hip/hip_runtime.h>
#include <math.h>

static constexpr int B  = 4096;
static constexpr int L  = 4096;
static constexpr int NX = B * 4;            // 16384 physical-param scalars
static constexpr int STATS_THREADS = 1024;  // one block computes mean/inv_std

typedef float f4 __attribute__((ext_vector_type(4)));

__device__ __constant__ float c_ps_powers[16] = {
    -5.0f, -4.0f, -3.0f, -2.0f, -1.5f, -1.0f, -0.5f, 0.0f,
     0.5f,  2.0f,  0.33333334f, 3.0f, 0.25f, 4.0f, 0.2f, 5.0f};

__device__ __constant__ float c_poly[5] = {2.0f, 5.0f, 8.0f, 11.0f, 14.0f};

// hardware transcendentals: v_log_f32 (log2), v_exp_f32 (2^x)
__device__ __forceinline__ float hw_log2(float x) { return __builtin_amdgcn_logf(x); }
__device__ __forceinline__ float hw_exp2(float x) { return __builtin_amdgcn_exp2f(x); }

// ---------------------------------------------------------------------------
// Kernel 1 (single block): mean and 1/std (ddof=1) of t = pp ** PS_POWERS.
// stats[0] = mean, stats[1] = inv_std
// ---------------------------------------------------------------------------
__global__ __launch_bounds__(STATS_THREADS)
void k_stats(const float* __restrict__ pp, float* __restrict__ stats) {
    const int tid = threadIdx.x;
    const f4* pp4 = reinterpret_cast<const f4*>(pp);
    double s = 0.0, s2 = 0.0;
    #pragma unroll
    for (int k = 0; k < NX / 4 / STATS_THREADS; ++k) {
        const f4 xv = pp4[tid + k * STATS_THREADS];
        #pragma unroll
        for (int c = 0; c < 4; ++c) {
            const float lx = hw_log2(xv[c]);
            float sf = 0.0f, sf2 = 0.0f;
            #pragma unroll
            for (int p = 0; p < 16; ++p) {
                const float t = hw_exp2(c_ps_powers[p] * lx);
                sf  += t;
                sf2 = fmaf(t, t, sf2);
            }
            s  += (double)sf;
            s2 += (double)sf2;
        }
    }
    __shared__ double sh_s[STATS_THREADS];
    __shared__ double sh_s2[STATS_THREADS];
    sh_s[tid] = s; sh_s2[tid] = s2;
    __syncthreads();
    for (int off = STATS_THREADS >> 1; off > 0; off >>= 1) {
        if (tid < off) {
            sh_s[tid]  += sh_s[tid + off];
            sh_s2[tid] += sh_s2[tid + off];
        }
        __syncthreads();
    }
    if (tid == 0) {
        const double n    = (double)(B * 64);
        const double mean = sh_s[0] / n;
        const double var  = (sh_s2[0] - n * mean * mean) / (n - 1.0);
        stats[0] = (float)mean;
        stats[1] = (float)(1.0 / sqrt(var));
    }
}

// ---------------------------------------------------------------------------
// Kernel 2: one wave per row — features + MLP -> 5 pre-scaled coefficients
// cc[row*8 + k] = coeff_k * poly_k   (stride 8 for alignment)
// ---------------------------------------------------------------------------
__global__ __launch_bounds__(64)
void k_coef(const float* __restrict__ pp,
            const float* __restrict__ W1, const float* __restrict__ b1,
            const float* __restrict__ W2, const float* __restrict__ b2,
            const float* __restrict__ stats, float* __restrict__ cc) {
    const int row = blockIdx.x;
    const int tid = threadIdx.x;

    __shared__ float sh_r[64];
    __shared__ float sh_h[32];

    const float x = pp[(row << 2) + (tid >> 4)];
    const float t = hw_exp2(c_ps_powers[tid & 15] * hw_log2(x));
    sh_r[tid] = fmaxf((t - stats[0]) * stats[1], 0.0f);
    __syncthreads();

    if (tid < 32) {
        float acc = b1[tid];
        const float* w = W1 + tid * 64;
        #pragma unroll
        for (int j = 0; j < 64; ++j) acc = fmaf(sh_r[j], w[j], acc);
        sh_h[tid] = acc;
    }
    __syncthreads();

    if (tid < 5) {
        float acc = b2[tid];
        const float* w = W2 + tid * 32;
        #pragma unroll
        for (int o = 0; o < 32; ++o) acc = fmaf(sh_h[o], w[o], acc);
        cc[row * 8 + tid] = acc * c_poly[tid];
    }
}

// ---------------------------------------------------------------------------
// Kernel 3: pure streaming. One block per row; 5 wave-uniform coefficient
// loads, then float4 stream of the eta row:
//   dy = c0'*e + c1'*e^4 + c2'*e^7 + c3'*e^10 + c4'*e^13
// ---------------------------------------------------------------------------
__device__ __forceinline__ float poly_eval(float e, float c0, float c1,
                                           float c2, float c3, float c4) {
    const float e3 = e * e * e;
    float w   = e;             // e^1
    float acc = c0 * w;
    w *= e3;                   // e^4
    acc = fmaf(c1, w, acc);
    w *= e3;                   // e^7
    acc = fmaf(c2, w, acc);
    w *= e3;                   // e^10
    acc = fmaf(c3, w, acc);
    w *= e3;                   // e^13
    acc = fmaf(c4, w, acc);
    return acc;
}

__global__ __launch_bounds__(256)
void k_stream(const float* __restrict__ eta, const float* __restrict__ cc,
              float* __restrict__ out) {
    const int row = blockIdx.x;
    const int tid = threadIdx.x;

    const float c0 = cc[row * 8 + 0];
    const float c1 = cc[row * 8 + 1];
    const float c2 = cc[row * 8 + 2];
    const float c3 = cc[row * 8 + 3];
    const float c4 = cc[row * 8 + 4];

    const f4* ep = reinterpret_cast<const f4*>(eta + (size_t)row * L);
    f4*       op = reinterpret_cast<f4*>(out + (size_t)row * L);

    #pragma unroll
    for (int i = tid; i < L / 4; i += 256) {
        const f4 e = ep[i];
        f4 r;
        r.x = poly_eval(e.x, c0, c1, c2, c3, c4);
        r.y = poly_eval(e.y, c0, c1, c2, c3, c4);
        r.z = poly_eval(e.z, c0, c1, c2, c3, c4);
        r.w = poly_eval(e.w, c0, c1, c2, c3, c4);
        op[i] = r;
    }
}

// ---------------------------------------------------------------------------
extern "C" void kernel_launch(void* const* d_in, const int* in_sizes, int n_in,
                              void* d_out, int out_size, void* d_ws, size_t ws_size,
                              hipStream_t stream) {
    const float* pp  = (const float*)d_in[0];   // [B,4]
    const float* eta = (const float*)d_in[1];   // [B,L]
    const float* W1  = (const float*)d_in[2];   // [32,64]
    const float* b1  = (const float*)d_in[3];   // [32]
    const float* W2  = (const float*)d_in[4];   // [5,32]
    const float* b2  = (const float*)d_in[5];   // [5]
    float* out = (float*)d_out;

    float* stats = (float*)d_ws;                // 2 floats
    float* cc    = stats + 8;                   // 4096*8 floats (128 KB)

    k_stats<<<1, STATS_THREADS, 0, stream>>>(pp, stats);
    k_coef<<<B, 64, 0, stream>>>(pp, W1, b1, W2, b2, stats, cc);
    k_stream<<<B, 256, 0, stream>>>(eta, cc, out);
}

// Round 5
// 41.533 us; speedup vs baseline: 1.0854x; 1.0854x over previous
//
#include <hip/hip_runtime.h>
#include <math.h>

static constexpr int B  = 4096;
static constexpr int L  = 4096;
static constexpr int NX = B * 4;            // 16384 physical-param scalars
static constexpr int STATS_THREADS = 1024;
static constexpr int ROWS_PER_BLK  = 4;     // fused kernel: rows per block

typedef float f4 __attribute__((ext_vector_type(4)));

__device__ __constant__ float c_ps_powers[16] = {
    -5.0f, -4.0f, -3.0f, -2.0f, -1.5f, -1.0f, -0.5f, 0.0f,
     0.5f,  2.0f,  0.33333334f, 3.0f, 0.25f, 4.0f, 0.2f, 5.0f};

__device__ __constant__ float c_poly[5] = {2.0f, 5.0f, 8.0f, 11.0f, 14.0f};

// hardware transcendentals: v_log_f32 (log2 x), v_exp_f32 (2^x)
__device__ __forceinline__ float hw_log2(float x) { return __builtin_amdgcn_logf(x); }
__device__ __forceinline__ float hw_exp2(float x) { return __builtin_amdgcn_exp2f(x); }

// ---------------------------------------------------------------------------
// Kernel 1 (single block): mean and 1/std (ddof=1) of t = pp ** PS_POWERS.
// stats[0] = mean, stats[1] = inv_std
// ---------------------------------------------------------------------------
__global__ __launch_bounds__(STATS_THREADS)
void k_stats(const float* __restrict__ pp, float* __restrict__ stats) {
    const int tid = threadIdx.x;
    const f4* pp4 = reinterpret_cast<const f4*>(pp);
    double s = 0.0, s2 = 0.0;
    #pragma unroll
    for (int k = 0; k < NX / 4 / STATS_THREADS; ++k) {
        const f4 xv = pp4[tid + k * STATS_THREADS];
        #pragma unroll
        for (int c = 0; c < 4; ++c) {
            const float lx = hw_log2(xv[c]);
            float sf = 0.0f, sf2 = 0.0f;
            #pragma unroll
            for (int p = 0; p < 16; ++p) {
                const float t = hw_exp2(c_ps_powers[p] * lx);
                sf  += t;
                sf2 = fmaf(t, t, sf2);
            }
            s  += (double)sf;
            s2 += (double)sf2;
        }
    }
    __shared__ double sh_s[STATS_THREADS];
    __shared__ double sh_s2[STATS_THREADS];
    sh_s[tid] = s; sh_s2[tid] = s2;
    __syncthreads();
    for (int off = STATS_THREADS >> 1; off > 0; off >>= 1) {
        if (tid < off) {
            sh_s[tid]  += sh_s[tid + off];
            sh_s2[tid] += sh_s2[tid + off];
        }
        __syncthreads();
    }
    if (tid == 0) {
        const double n    = (double)(B * 64);
        const double mean = sh_s[0] / n;
        const double var  = (sh_s2[0] - n * mean * mean) / (n - 1.0);
        stats[0] = (float)mean;
        stats[1] = (float)(1.0 / sqrt(var));
    }
}

// ---------------------------------------------------------------------------
// Kernel 2: 4 rows per block. Prologue computes 4 rows' MLP coefficients in
// LDS (amortized, overlapped with other blocks' streaming), then all 256
// threads stream the 4 eta rows with plain (cacheable) float4 accesses.
//   dy = c0'*e + c1'*e^4 + c2'*e^7 + c3'*e^10 + c4'*e^13   (ck' = ck * p_k)
// ---------------------------------------------------------------------------
__device__ __forceinline__ float poly_eval(float e, float c0, float c1,
                                           float c2, float c3, float c4) {
    const float e3 = e * e * e;
    float w   = e;             // e^1
    float acc = c0 * w;
    w *= e3;                   // e^4
    acc = fmaf(c1, w, acc);
    w *= e3;                   // e^7
    acc = fmaf(c2, w, acc);
    w *= e3;                   // e^10
    acc = fmaf(c3, w, acc);
    w *= e3;                   // e^13
    acc = fmaf(c4, w, acc);
    return acc;
}

__global__ __launch_bounds__(256)
void k_fused(const float* __restrict__ pp,  const float* __restrict__ eta,
             const float* __restrict__ W1,  const float* __restrict__ b1,
             const float* __restrict__ W2,  const float* __restrict__ b2,
             const float* __restrict__ stats, float* __restrict__ out) {
    const int blk = blockIdx.x;               // rows 4*blk .. 4*blk+3
    const int tid = threadIdx.x;
    const int row0 = blk * ROWS_PER_BLK;

    __shared__ float sh_r[ROWS_PER_BLK][64];  // relu(norm) features
    __shared__ float sh_h[ROWS_PER_BLK][32];  // hidden layer
    __shared__ float sh_c[ROWS_PER_BLK][8];   // scaled coefficients

    // phase 1: features. tid -> (row r = tid>>6, feature j = tid&63)
    {
        const float mean    = stats[0];
        const float inv_std = stats[1];
        const int r = tid >> 6;
        const int j = tid & 63;
        const float x = pp[(row0 + r) * 4 + (j >> 4)];
        const float t = hw_exp2(c_ps_powers[j & 15] * hw_log2(x));
        sh_r[r][j] = fmaxf((t - mean) * inv_std, 0.0f);
    }
    __syncthreads();

    // phase 2: hidden layer. 128 threads: (row r = tid>>5, neuron h = tid&31)
    if (tid < 128) {
        const int r = tid >> 5;
        const int h = tid & 31;
        float acc = b1[h];
        const float* w = W1 + h * 64;
        #pragma unroll
        for (int j = 0; j < 64; ++j) acc = fmaf(sh_r[r][j], w[j], acc);
        sh_h[r][h] = acc;
    }
    __syncthreads();

    // phase 3: output layer. 32 threads: (row r = tid>>3, coef k = tid&7)
    if (tid < 32) {
        const int r = tid >> 3;
        const int k = tid & 7;
        if (k < 5) {
            float acc = b2[k];
            const float* w = W2 + k * 32;
            #pragma unroll
            for (int o = 0; o < 32; ++o) acc = fmaf(sh_h[r][o], w[o], acc);
            sh_c[r][k] = acc * c_poly[k];
        }
    }
    __syncthreads();

    // phase 4: stream 4 rows, 4 float4 per thread per row
    #pragma unroll
    for (int rr = 0; rr < ROWS_PER_BLK; ++rr) {
        const float c0 = sh_c[rr][0], c1 = sh_c[rr][1], c2 = sh_c[rr][2],
                    c3 = sh_c[rr][3], c4 = sh_c[rr][4];
        const f4* ep = reinterpret_cast<const f4*>(eta + (size_t)(row0 + rr) * L);
        f4*       op = reinterpret_cast<f4*>(out + (size_t)(row0 + rr) * L);
        #pragma unroll
        for (int it = 0; it < L / 4 / 256; ++it) {
            const int i = tid + it * 256;
            const f4 e = ep[i];
            f4 r;
            r.x = poly_eval(e.x, c0, c1, c2, c3, c4);
            r.y = poly_eval(e.y, c0, c1, c2, c3, c4);
            r.z = poly_eval(e.z, c0, c1, c2, c3, c4);
            r.w = poly_eval(e.w, c0, c1, c2, c3, c4);
            op[i] = r;
        }
    }
}

// ---------------------------------------------------------------------------
extern "C" void kernel_launch(void* const* d_in, const int* in_sizes, int n_in,
                              void* d_out, int out_size, void* d_ws, size_t ws_size,
                              hipStream_t stream) {
    const float* pp  = (const float*)d_in[0];   // [B,4]
    const float* eta = (const float*)d_in[1];   // [B,L]
    const float* W1  = (const float*)d_in[2];   // [32,64]
    const float* b1  = (const float*)d_in[3];   // [32]
    const float* W2  = (const float*)d_in[4];   // [5,32]
    const float* b2  = (const float*)d_in[5];   // [5]
    float* out = (float*)d_out;

    float* stats = (float*)d_ws;                // 2 floats

    k_stats<<<1, STATS_THREADS, 0, stream>>>(pp, stats);
    k_fused<<<B / ROWS_PER_BLK, 256, 0, stream>>>(pp, eta, W1, b1, W2, b2,
                                                  stats, out);
}